// Round 4
// baseline (446.992 us; speedup 1.0000x reference)
//
#include <hip/hip_runtime.h>
#include <hip/hip_bf16.h>

#define T_ 8
#define N0_ 32
#define N1_ 32
#define SP_ (N0_*N1_)   /* 1024 spatial cells */
#define S_ (T_*SP_)     /* 8192 space-time cells */
#define E_ 256
#define P_ 16
#define NH_ 8
#define HD_ 32

typedef __attribute__((ext_vector_type(8))) short short8;
typedef __attribute__((ext_vector_type(4))) float f32x4;
typedef __attribute__((ext_vector_type(8))) unsigned short u16x8;

__device__ __forceinline__ unsigned short f2bf(float f) {
  __hip_bfloat16 h = __float2bfloat16(f);
  return *reinterpret_cast<unsigned short*>(&h);
}
__device__ __forceinline__ float bf2f(unsigned short u) {
  return __uint_as_float((unsigned)u << 16);
}

// ---------------- stats: xmin & spacing per batch (matches reference fp32 ops) ------------
__global__ void stats_kernel(const float* __restrict__ tg, const float* __restrict__ grid,
                             float* __restrict__ stats, int m) {
  int lane = threadIdx.x;  // 64 threads, 1 block
  float mn0 = 1e30f, mx0 = -1e30f, mn1 = 1e30f, mx1 = -1e30f;
  for (int i = lane; i < SP_; i += 64) {
    float g0 = grid[i*2], g1 = grid[i*2+1];
    mn0 = fminf(mn0, g0); mx0 = fmaxf(mx0, g0);
    mn1 = fminf(mn1, g1); mx1 = fmaxf(mx1, g1);
  }
  for (int msk = 32; msk; msk >>= 1) {
    mn0 = fminf(mn0, __shfl_xor(mn0, msk));
    mx0 = fmaxf(mx0, __shfl_xor(mx0, msk));
    mn1 = fminf(mn1, __shfl_xor(mn1, msk));
    mx1 = fmaxf(mx1, __shfl_xor(mx1, msk));
  }
  if (lane == 0) {
    for (int b = 0; b < m; ++b) {
      float tmn = 1e30f, tmx = -1e30f;
      for (int t = 0; t < T_; ++t) {
        float v = tg[b*T_ + t];
        tmn = fminf(tmn, v); tmx = fmaxf(tmx, v);
      }
      float* st = stats + b*8;
      st[0] = tmn; st[1] = mn0; st[2] = mn1;
      st[3] = (tmx - tmn) / (float)(T_ - 1);
      st[4] = (mx0 - mn0) / (float)(N0_ - 1);
      st[5] = (mx1 - mn1) / (float)(N1_ - 1);
    }
  }
}

// ---------------- x_grid output ------------------------------------------------------------
__global__ void xgrid_kernel(const float* __restrict__ tg, const float* __restrict__ grid,
                             float* __restrict__ out, int total) {
  int idx = blockIdx.x * blockDim.x + threadIdx.x;  // over m*T*1024
  if (idx >= total) return;
  int sp = idx & (SP_ - 1);
  int bt = idx >> 10;
  out[idx*3 + 0] = tg[bt];
  out[idx*3 + 1] = grid[sp*2 + 0];
  out[idx*3 + 2] = grid[sp*2 + 1];
}

// ---------------- point -> cell assignment (fp32 op order == reference) --------------------
__global__ void assign_kernel(const float* __restrict__ x, const float* __restrict__ stats,
                              int* __restrict__ counts, int* __restrict__ cell_raw,
                              int m, int n) {
  int i = blockIdx.x * blockDim.x + threadIdx.x;
  if (i >= m*n) return;
  int b = i / n;
  int j = i - b*n;
  const float* st = stats + b*8;
  float xt = x[(size_t)i*3 + 0], x0 = x[(size_t)i*3 + 1], x1 = x[(size_t)i*3 + 2];
  float m0 = floorf((xt - st[0] + st[3]*0.5f) / st[3]);
  float m1 = floorf((x0 - st[1] + st[4]*0.5f) / st[4]);
  float m2 = floorf((x1 - st[2] + st[5]*0.5f) / st[5]);
  m0 = fminf(fmaxf(m0, 0.f), (float)(T_ - 1));
  m1 = fminf(fmaxf(m1, 0.f), (float)(N0_ - 1));
  m2 = fminf(fmaxf(m2, 0.f), (float)(N1_ - 1));
  int s = (int)m0 * SP_ + (int)m1 * N1_ + (int)m2;
  int cg = b * S_ + s;
  int old = atomicAdd(&counts[cg], 1);
  if (old < P_) cell_raw[(size_t)cg * P_ + old] = j;
}

// ------- per-cell: sort indices (determinism + exact first-15 drop), pack eff+pts ---------
__global__ void finalize_kernel(const int* __restrict__ counts, int* __restrict__ cell_raw,
                                int* __restrict__ pts2, int total) {
  int cg = blockIdx.x * blockDim.x + threadIdx.x;
  if (cg >= total) return;
  int cnt = counts[cg];
  int stored = cnt < P_ ? cnt : P_;
  int eff = cnt < (P_ - 1) ? cnt : (P_ - 1);
  int* p = cell_raw + (size_t)cg * P_;
  for (int i = 1; i < stored; ++i) {   // insertion sort ascending (original index order)
    int key = p[i]; int j = i - 1;
    while (j >= 0 && p[j] > key) { p[j+1] = p[j]; --j; }
    p[j+1] = key;
  }
  int* o = pts2 + (size_t)cg * P_;
  o[0] = eff;
  for (int i = 0; i < eff; ++i) o[1 + i] = p[i];
}

// ---------------- weight transpose+convert: wT[1024][256] bf16 = [Wq|Wk|Wv|Wo]^T ----------
__global__ __launch_bounds__(256) void wtrans_kernel(const float* __restrict__ Wq,
                                                     const float* __restrict__ Wk,
                                                     const float* __restrict__ Wv,
                                                     const float* __restrict__ Wo,
                                                     unsigned short* __restrict__ wT) {
  int mat = blockIdx.x >> 4;
  int tile = blockIdx.x & 15;
  int tr = (tile >> 2) * 64;   // row (k) offset in W
  int tc = (tile & 3) * 64;    // col offset in W
  const float* W = mat == 0 ? Wq : mat == 1 ? Wk : mat == 2 ? Wv : Wo;
  __shared__ float ts[64][65];
  int t = threadIdx.x;
  int r = t >> 2, c0 = (t & 3) * 16;
#pragma unroll
  for (int i = 0; i < 4; ++i) {
    float4 v = *(const float4*)&W[(size_t)(tr + r) * 256 + tc + c0 + i*4];
    ts[r][c0 + i*4 + 0] = v.x; ts[r][c0 + i*4 + 1] = v.y;
    ts[r][c0 + i*4 + 2] = v.z; ts[r][c0 + i*4 + 3] = v.w;
  }
  __syncthreads();
  u16x8 o0, o1;
#pragma unroll
  for (int i = 0; i < 8; ++i) o0[i] = f2bf(ts[c0 + i][r]);
#pragma unroll
  for (int i = 0; i < 8; ++i) o1[i] = f2bf(ts[c0 + 8 + i][r]);
  unsigned short* dst = wT + (size_t)(mat * 256 + tc + r) * 256 + tr + c0;
  *(u16x8*)dst = o0;
  *(u16x8*)(dst + 8) = o1;
}

// ============ persistent-B streaming GEMM: C[M,N] = A[M,256] @ BT[N,256]^T ================
// Block: 512 thr / 8 waves. B col-panel (128 cols x K=256, bf16, 64KB) staged in LDS ONCE
// (XOR-swizzled), single barrier, then each wave streams 32 A-rows with full-K sweep:
// A global->reg (dense 128B/row/kf), 1-deep prefetch, zero further barriers.
template <typename InT, typename OutT>
__global__ __launch_bounds__(512, 4) void gemm_bpanel(const InT* __restrict__ A,
                                                      const unsigned short* __restrict__ BT,
                                                      OutT* __restrict__ C,
                                                      int M, int ldc, int CP) {
  __shared__ unsigned short Bs[128 * 256];
  int tid = threadIdx.x;
  int bid = blockIdx.x;
  int cp = bid % CP;                  // col-panel; cp-siblings adjacent -> spread over XCDs
  int rb = bid / CP;
  int RB = gridDim.x / CP;
  int nrc = M >> 8;                   // 256-row chunks

  // ---- stage B panel: rows [cp*128, cp*128+128) of BT, swizzled ----
  {
    int row = tid >> 2;
    int c0 = (tid & 3) * 64;
    const unsigned short* src = BT + (size_t)(cp * 128 + row) * 256 + c0;
    unsigned swz = (unsigned)(row & 7) << 4;
#pragma unroll
    for (int i = 0; i < 8; ++i) {
      u16x8 v = *(const u16x8*)(src + i * 8);
      *(u16x8*)((char*)Bs + row * 512 + ((unsigned)((c0 + i * 8) * 2) ^ swz)) = v;
    }
  }
  __syncthreads();

  int lane = tid & 63;
  int wid = tid >> 6;                 // 8 waves x 32 rows = 256 rows/chunk
  int l15 = lane & 15;
  int slot = lane >> 4;               // 0..3
  int koff = slot * 8;                // k sub-offset within kf*32
  unsigned sx = (unsigned)(l15 & 7) << 4;   // read-side swizzle (row&7 == l15&7)

  for (int rc = rb; rc < nrc; rc += RB) {
    int r0 = (rc << 8) + wid * 32 + l15;     // group-0 row; group-1 = r0+16
    f32x4 acc0[8] = {};
    f32x4 acc1[8] = {};

    float4 f00, f01, f10, f11;               // fp32 prefetch regs
    u16x8 h0, h1;                            // bf16 prefetch regs
    auto LOADA = [&](int kf) {
      if constexpr (__is_same(InT, float)) {
        const float* a0 = A + (size_t)r0 * 256 + kf * 32 + koff;
        const float* a1 = A + (size_t)(r0 + 16) * 256 + kf * 32 + koff;
        f00 = *(const float4*)a0; f01 = *(const float4*)(a0 + 4);
        f10 = *(const float4*)a1; f11 = *(const float4*)(a1 + 4);
      } else {
        const unsigned short* a0 = (const unsigned short*)A + (size_t)r0 * 256 + kf * 32 + koff;
        const unsigned short* a1 = (const unsigned short*)A + (size_t)(r0 + 16) * 256 + kf * 32 + koff;
        h0 = *(const u16x8*)a0;
        h1 = *(const u16x8*)a1;
      }
    };
    LOADA(0);
#pragma unroll
    for (int kf = 0; kf < 8; ++kf) {
      short8 af0, af1;
      if constexpr (__is_same(InT, float)) {
        af0[0]=f2bf(f00.x); af0[1]=f2bf(f00.y); af0[2]=f2bf(f00.z); af0[3]=f2bf(f00.w);
        af0[4]=f2bf(f01.x); af0[5]=f2bf(f01.y); af0[6]=f2bf(f01.z); af0[7]=f2bf(f01.w);
        af1[0]=f2bf(f10.x); af1[1]=f2bf(f10.y); af1[2]=f2bf(f10.z); af1[3]=f2bf(f10.w);
        af1[4]=f2bf(f11.x); af1[5]=f2bf(f11.y); af1[6]=f2bf(f11.z); af1[7]=f2bf(f11.w);
      } else {
        af0 = (short8)h0;
        af1 = (short8)h1;
      }
      if (kf < 7) LOADA(kf + 1);
      unsigned bcol = (unsigned)(kf * 64 + slot * 16) ^ sx;
#pragma unroll
      for (int nn = 0; nn < 8; ++nn) {
        short8 bf = *(const short8*)((const char*)Bs + (nn * 16 + l15) * 512 + bcol);
        acc0[nn] = __builtin_amdgcn_mfma_f32_16x16x32_bf16(af0, bf, acc0[nn], 0, 0, 0);
        acc1[nn] = __builtin_amdgcn_mfma_f32_16x16x32_bf16(af1, bf, acc1[nn], 0, 0, 0);
      }
    }
    // ---- epilogue: C/D layout col=lane&15, row=(lane>>4)*4+j ----
    int rbase = (rc << 8) + wid * 32 + slot * 4;
#pragma unroll
    for (int nn = 0; nn < 8; ++nn) {
      int gcol = cp * 128 + nn * 16 + l15;
#pragma unroll
      for (int j = 0; j < 4; ++j) {
        size_t o0 = (size_t)(rbase + j) * ldc + gcol;
        size_t o1 = (size_t)(rbase + 16 + j) * ldc + gcol;
        if constexpr (__is_same(OutT, float)) {
          C[o0] = acc0[nn][j];
          C[o1] = acc1[nn][j];
        } else {
          C[o0] = __float2bfloat16(acc0[nn][j]);
          C[o1] = __float2bfloat16(acc1[nn][j]);
        }
      }
    }
  }
}

// ---------------- masked cross-attention: one wave per cell, online softmax ---------------
__global__ __launch_bounds__(256) void attn_kernel(
    const float* __restrict__ lat,          // [1024][768]  q|k|v
    const __hip_bfloat16* __restrict__ kv,  // [m*n][512]   k|v
    const int* __restrict__ pts2,           // [MS][16]: w0=eff, w1..15 sorted pt indices
    __hip_bfloat16* __restrict__ attn_out, int n) {
  const float scale = 0.17677669529663687f;  // 1/sqrt(32)
  int wid = threadIdx.x >> 6;
  int lane = threadIdx.x & 63;
  int cellg = blockIdx.x * 4 + wid;
  int b = cellg >> 13;                 // S_=8192, cells per batch
  int c = cellg & (SP_ - 1);           // spatial index -> latent row
  int d0 = lane << 2;                  // 4 dims per lane

  const int* pp = pts2 + (size_t)cellg * P_;
  int4 h0 = *(const int4*)pp;          // eff, pt0, pt1, pt2 (broadcast load)
  int eff = h0.x;

  const float* latc = lat + c * 768 + d0;
  float4 q  = *(const float4*)latc;
  float4 kl = *(const float4*)(latc + 256);
  float4 vl = *(const float4*)(latc + 512);

  // grid-token logit -> init online-softmax state
  float part = q.x*kl.x + q.y*kl.y + q.z*kl.z + q.w*kl.w;
  part += __shfl_xor(part, 1);
  part += __shfl_xor(part, 2);
  part += __shfl_xor(part, 4);         // head-local (8 lanes = 32 dims)
  float mx = part * scale;
  float ssum = 1.f;
  float4 acc = vl;

  const unsigned short* kvp = (const unsigned short*)kv;
  size_t bbase = (size_t)b * n;

  int pt[4]; pt[0] = h0.y; pt[1] = h0.z; pt[2] = h0.w; pt[3] = 0;
  int done = 0, cap = 3;
  while (done < eff) {
    int np = eff - done; if (np > cap) np = cap;
    ushort4 kr[4], vr[4];
#pragma unroll
    for (int i = 0; i < 4; ++i) if (i < np) {
      size_t row = (bbase + (size_t)pt[i]) * 512;
      kr[i] = *(const ushort4*)(kvp + row + d0);
      vr[i] = *(const ushort4*)(kvp + row + 256 + d0);
    }
#pragma unroll
    for (int i = 0; i < 4; ++i) if (i < np) {
      float p = q.x*bf2f(kr[i].x) + q.y*bf2f(kr[i].y) + q.z*bf2f(kr[i].z) + q.w*bf2f(kr[i].w);
      p += __shfl_xor(p, 1);
      p += __shfl_xor(p, 2);
      p += __shfl_xor(p, 4);
      p *= scale;
      float m2 = fmaxf(mx, p);
      float corr = __expf(mx - m2);
      float e = __expf(p - m2);
      ssum = ssum * corr + e;
      acc.x = acc.x * corr + e * bf2f(vr[i].x);
      acc.y = acc.y * corr + e * bf2f(vr[i].y);
      acc.z = acc.z * corr + e * bf2f(vr[i].z);
      acc.w = acc.w * corr + e * bf2f(vr[i].w);
      mx = m2;
    }
    done += np;
    cap = 4;
    if (done < eff) {
      int4 h = *(const int4*)(pp + 1 + done);   // done in {3,7,11} -> aligned
      pt[0] = h.x; pt[1] = h.y; pt[2] = h.z; pt[3] = h.w;
    }
  }
  float inv = 1.f / ssum;
  ushort4 o;
  o.x = f2bf(acc.x * inv); o.y = f2bf(acc.y * inv);
  o.z = f2bf(acc.z * inv); o.w = f2bf(acc.w * inv);
  *(ushort4*)((unsigned short*)attn_out + (size_t)cellg * E_ + d0) = o;
}

// -------------------------------------------------------------------------------------------
extern "C" void kernel_launch(void* const* d_in, const int* in_sizes, int n_in,
                              void* d_out, int out_size, void* d_ws, size_t ws_size,
                              hipStream_t stream) {
  const float* x       = (const float*)d_in[0];
  const float* z       = (const float*)d_in[1];
  const float* tg      = (const float*)d_in[2];
  const float* latents = (const float*)d_in[3];
  const float* grid    = (const float*)d_in[4];
  const float* Wq      = (const float*)d_in[5];
  const float* Wk      = (const float*)d_in[6];
  const float* Wv      = (const float*)d_in[7];
  const float* Wo      = (const float*)d_in[8];

  int m = in_sizes[2] / T_;              // 4
  int n = in_sizes[1] / (m * E_);        // 16384
  int MS = m * S_;                       // 32768
  float* out = (float*)d_out;

  // ---- workspace carve (256B aligned) ----
  char* w = (char*)d_ws;
  auto alloc = [&](size_t bytes) { char* p = w; w += (bytes + 255) & ~(size_t)255; return p; };
  float* stats      = (float*)alloc((size_t)m * 8 * 4);
  int*   counts     = (int*)  alloc((size_t)MS * 4);
  int*   cell_raw   = (int*)  alloc((size_t)MS * P_ * 4);
  int*   pts2       = (int*)  alloc((size_t)MS * P_ * 4);
  unsigned short* wT = (unsigned short*)alloc((size_t)1024 * 256 * 2);
  float* lat        = (float*)alloc((size_t)SP_ * 768 * 4);
  __hip_bfloat16* kv       = (__hip_bfloat16*)alloc((size_t)m * n * 512 * 2);
  __hip_bfloat16* attn_out = (__hip_bfloat16*)alloc((size_t)MS * E_ * 2);

  hipMemsetAsync(counts, 0, (size_t)MS * 4, stream);
  stats_kernel<<<1, 64, 0, stream>>>(tg, grid, stats, m);

  int tot_xg = m * T_ * SP_;             // 32768 grid sites
  xgrid_kernel<<<(tot_xg + 255)/256, 256, 0, stream>>>(tg, grid, out, tot_xg);

  assign_kernel<<<(m*n + 255)/256, 256, 0, stream>>>(x, stats, counts, cell_raw, m, n);
  finalize_kernel<<<(MS + 255)/256, 256, 0, stream>>>(counts, cell_raw, pts2, MS);

  // weights: transpose + convert to bf16  [Wq|Wk|Wv|Wo]^T
  wtrans_kernel<<<64, 256, 0, stream>>>(Wq, Wk, Wv, Wo, wT);

  // latent projections fused: lat[1024,768] = latents @ [Wq|Wk|Wv]  (CP=6, nrc=4 -> 24 blocks)
  gemm_bpanel<float, float><<<24, 512, 0, stream>>>(latents, wT, lat, SP_, 768, 6);

  // point projections fused: kv[m*n,512] = z @ [Wk|Wv]  (CP=4, nrc=256 -> 1024 blocks)
  gemm_bpanel<float, __hip_bfloat16><<<1024, 512, 0, stream>>>(
      z, wT + (size_t)256*256, (__hip_bfloat16*)kv, m*n, 512, 4);

  // attention: one wave per cell
  attn_kernel<<<MS/4, 256, 0, stream>>>(lat, kv, pts2, attn_out, n);

  // output projection -> z_grid  (CP=2, nrc=128 -> 256 blocks)
  gemm_bpanel<__hip_bfloat16, float><<<256, 512, 0, stream>>>(
      attn_out, wT + (size_t)768*256, out + (size_t)tot_xg * 3, MS, 256, 2);
}

// Round 5
// 161.374 us; speedup vs baseline: 2.7699x; 2.7699x over previous
//
#include <hip/hip_runtime.h>
#include <hip/hip_bf16.h>

#define T_ 8
#define N0_ 32
#define N1_ 32
#define SP_ (N0_*N1_)   /* 1024 spatial cells */
#define S_ (T_*SP_)     /* 8192 space-time cells */
#define E_ 256
#define P_ 16
#define NH_ 8
#define HD_ 32

typedef __attribute__((ext_vector_type(8))) short short8;
typedef __attribute__((ext_vector_type(4))) float f32x4;
typedef __attribute__((ext_vector_type(8))) unsigned short u16x8;

__device__ __forceinline__ unsigned short f2bf(float f) {
  __hip_bfloat16 h = __float2bfloat16(f);
  return *reinterpret_cast<unsigned short*>(&h);
}
__device__ __forceinline__ float bf2f(unsigned short u) {
  return __uint_as_float((unsigned)u << 16);
}

// ---------------- stats: xmin & spacing per batch (matches reference fp32 ops) ------------
__global__ void stats_kernel(const float* __restrict__ tg, const float* __restrict__ grid,
                             float* __restrict__ stats, int m) {
  int lane = threadIdx.x;  // 64 threads, 1 block
  float mn0 = 1e30f, mx0 = -1e30f, mn1 = 1e30f, mx1 = -1e30f;
  for (int i = lane; i < SP_; i += 64) {
    float g0 = grid[i*2], g1 = grid[i*2+1];
    mn0 = fminf(mn0, g0); mx0 = fmaxf(mx0, g0);
    mn1 = fminf(mn1, g1); mx1 = fmaxf(mx1, g1);
  }
  for (int msk = 32; msk; msk >>= 1) {
    mn0 = fminf(mn0, __shfl_xor(mn0, msk));
    mx0 = fmaxf(mx0, __shfl_xor(mx0, msk));
    mn1 = fminf(mn1, __shfl_xor(mn1, msk));
    mx1 = fmaxf(mx1, __shfl_xor(mx1, msk));
  }
  if (lane == 0) {
    for (int b = 0; b < m; ++b) {
      float tmn = 1e30f, tmx = -1e30f;
      for (int t = 0; t < T_; ++t) {
        float v = tg[b*T_ + t];
        tmn = fminf(tmn, v); tmx = fmaxf(tmx, v);
      }
      float* st = stats + b*8;
      st[0] = tmn; st[1] = mn0; st[2] = mn1;
      st[3] = (tmx - tmn) / (float)(T_ - 1);
      st[4] = (mx0 - mn0) / (float)(N0_ - 1);
      st[5] = (mx1 - mn1) / (float)(N1_ - 1);
    }
  }
}

// ---------------- x_grid output ------------------------------------------------------------
__global__ void xgrid_kernel(const float* __restrict__ tg, const float* __restrict__ grid,
                             float* __restrict__ out, int total) {
  int idx = blockIdx.x * blockDim.x + threadIdx.x;  // over m*T*1024
  if (idx >= total) return;
  int sp = idx & (SP_ - 1);
  int bt = idx >> 10;
  out[idx*3 + 0] = tg[bt];
  out[idx*3 + 1] = grid[sp*2 + 0];
  out[idx*3 + 2] = grid[sp*2 + 1];
}

// ---------------- point -> cell assignment (fp32 op order == reference) --------------------
__global__ void assign_kernel(const float* __restrict__ x, const float* __restrict__ stats,
                              int* __restrict__ counts, int* __restrict__ cell_raw,
                              int m, int n) {
  int i = blockIdx.x * blockDim.x + threadIdx.x;
  if (i >= m*n) return;
  int b = i / n;
  int j = i - b*n;
  const float* st = stats + b*8;
  float xt = x[(size_t)i*3 + 0], x0 = x[(size_t)i*3 + 1], x1 = x[(size_t)i*3 + 2];
  float m0 = floorf((xt - st[0] + st[3]*0.5f) / st[3]);
  float m1 = floorf((x0 - st[1] + st[4]*0.5f) / st[4]);
  float m2 = floorf((x1 - st[2] + st[5]*0.5f) / st[5]);
  m0 = fminf(fmaxf(m0, 0.f), (float)(T_ - 1));
  m1 = fminf(fmaxf(m1, 0.f), (float)(N0_ - 1));
  m2 = fminf(fmaxf(m2, 0.f), (float)(N1_ - 1));
  int s = (int)m0 * SP_ + (int)m1 * N1_ + (int)m2;
  int cg = b * S_ + s;
  int old = atomicAdd(&counts[cg], 1);
  if (old < P_) cell_raw[(size_t)cg * P_ + old] = j;
}

// ------- per-cell: sort indices (determinism + exact first-15 drop), pack eff+pts ---------
__global__ void finalize_kernel(const int* __restrict__ counts, int* __restrict__ cell_raw,
                                int* __restrict__ pts2, int total) {
  int cg = blockIdx.x * blockDim.x + threadIdx.x;
  if (cg >= total) return;
  int cnt = counts[cg];
  int stored = cnt < P_ ? cnt : P_;
  int eff = cnt < (P_ - 1) ? cnt : (P_ - 1);
  int* p = cell_raw + (size_t)cg * P_;
  for (int i = 1; i < stored; ++i) {   // insertion sort ascending (original index order)
    int key = p[i]; int j = i - 1;
    while (j >= 0 && p[j] > key) { p[j+1] = p[j]; --j; }
    p[j+1] = key;
  }
  int* o = pts2 + (size_t)cg * P_;
  o[0] = eff;
  for (int i = 0; i < eff; ++i) o[1 + i] = p[i];
}

// ---------------- weight transpose+convert: wT[1024][256] bf16 = [Wq|Wk|Wv|Wo]^T ----------
__global__ __launch_bounds__(256) void wtrans_kernel(const float* __restrict__ Wq,
                                                     const float* __restrict__ Wk,
                                                     const float* __restrict__ Wv,
                                                     const float* __restrict__ Wo,
                                                     unsigned short* __restrict__ wT) {
  int mat = blockIdx.x >> 4;
  int tile = blockIdx.x & 15;
  int tr = (tile >> 2) * 64;   // row (k) offset in W
  int tc = (tile & 3) * 64;    // col offset in W
  const float* W = mat == 0 ? Wq : mat == 1 ? Wk : mat == 2 ? Wv : Wo;
  __shared__ float ts[64][65];
  int t = threadIdx.x;
  int r = t >> 2, c0 = (t & 3) * 16;
#pragma unroll
  for (int i = 0; i < 4; ++i) {
    float4 v = *(const float4*)&W[(size_t)(tr + r) * 256 + tc + c0 + i*4];
    ts[r][c0 + i*4 + 0] = v.x; ts[r][c0 + i*4 + 1] = v.y;
    ts[r][c0 + i*4 + 2] = v.z; ts[r][c0 + i*4 + 3] = v.w;
  }
  __syncthreads();
  u16x8 o0, o1;
#pragma unroll
  for (int i = 0; i < 8; ++i) o0[i] = f2bf(ts[c0 + i][r]);
#pragma unroll
  for (int i = 0; i < 8; ++i) o1[i] = f2bf(ts[c0 + 8 + i][r]);
  unsigned short* dst = wT + (size_t)(mat * 256 + tc + r) * 256 + tr + c0;
  *(u16x8*)dst = o0;
  *(u16x8*)(dst + 8) = o1;
}

// ============ persistent-B streaming GEMM: C[M,N] = A[M,256] @ BT[N,256]^T ================
// 512 thr / 8 waves. B col-panel (128 x 256 bf16 = 64KB) staged in LDS once (XOR-swizzle),
// ONE barrier, then waves stream their private A rows global->reg, full-K sweep, no
// further barriers. Wave tile 32x64: acc 32 regs -> fits 128-reg budget (no spill).
template <typename InT, typename OutT>
__global__ __launch_bounds__(512, 4) void gemm_bpanel(const InT* __restrict__ A,
                                                      const unsigned short* __restrict__ BT,
                                                      OutT* __restrict__ C,
                                                      int M, int ldc, int CP) {
  __shared__ unsigned short Bs[128 * 256];
  int tid = threadIdx.x;
  int nb = gridDim.x;
  int bid = blockIdx.x;
  int L = bid;
  if ((nb & 7) == 0) L = (bid & 7) * (nb >> 3) + (bid >> 3);   // XCD-chunked
  int rp = L / CP;
  int cp = L - rp * CP;

  // ---- stage B panel rows [cp*128, +128) of BT, swizzled; one-time cost ----
  {
    int row = tid >> 2;              // 0..127 (C-col)
    int c0 = (tid & 3) * 64;         // k-elem offset
    const unsigned short* src = BT + (size_t)(cp * 128 + row) * 256 + c0;
    unsigned swz = (unsigned)(row & 7) << 4;
#pragma unroll
    for (int i = 0; i < 8; ++i) {
      u16x8 v = *(const u16x8*)(src + i * 8);
      *(u16x8*)((char*)Bs + row * 512 + (((unsigned)(c0 + i * 8) * 2) ^ swz)) = v;
    }
  }
  __syncthreads();

  int lane = tid & 63;
  int wid = tid >> 6;
  int l15 = lane & 15;
  int slot = lane >> 4;              // 0..3
  int wr = (wid >> 1) * 32;          // wave row offset (4 groups)
  int wc = (wid & 1) * 64;           // wave col offset (2 groups)
  unsigned sx = (unsigned)(l15 & 7) << 4;

  int r0 = rp * 128 + wr + l15;      // A row, group 0; group 1 = r0+16
  int koff = slot * 8;

  f32x4 acc0[4] = {};
  f32x4 acc1[4] = {};

  float4 f00, f01, f10, f11;         // fp32 prefetch
  u16x8 h0, h1;                      // bf16 prefetch
  auto LOADA = [&](int kf) {
    if constexpr (__is_same(InT, float)) {
      const float* a0 = A + (size_t)r0 * 256 + kf * 32 + koff;
      const float* a1 = A + (size_t)(r0 + 16) * 256 + kf * 32 + koff;
      f00 = *(const float4*)a0; f01 = *(const float4*)(a0 + 4);
      f10 = *(const float4*)a1; f11 = *(const float4*)(a1 + 4);
    } else {
      const unsigned short* a0 = (const unsigned short*)A + (size_t)r0 * 256 + kf * 32 + koff;
      const unsigned short* a1 = (const unsigned short*)A + (size_t)(r0 + 16) * 256 + kf * 32 + koff;
      h0 = *(const u16x8*)a0;
      h1 = *(const u16x8*)a1;
    }
  };
  LOADA(0);
#pragma unroll
  for (int kf = 0; kf < 8; ++kf) {
    short8 af0, af1;
    if constexpr (__is_same(InT, float)) {
      af0[0]=f2bf(f00.x); af0[1]=f2bf(f00.y); af0[2]=f2bf(f00.z); af0[3]=f2bf(f00.w);
      af0[4]=f2bf(f01.x); af0[5]=f2bf(f01.y); af0[6]=f2bf(f01.z); af0[7]=f2bf(f01.w);
      af1[0]=f2bf(f10.x); af1[1]=f2bf(f10.y); af1[2]=f2bf(f10.z); af1[3]=f2bf(f10.w);
      af1[4]=f2bf(f11.x); af1[5]=f2bf(f11.y); af1[6]=f2bf(f11.z); af1[7]=f2bf(f11.w);
    } else {
      af0 = (short8)h0;
      af1 = (short8)h1;
    }
    if (kf < 7) LOADA(kf + 1);
    unsigned bbase = (unsigned)(kf * 64 + slot * 16) ^ sx;
#pragma unroll
    for (int nn = 0; nn < 4; ++nn) {
      short8 bf = *(const short8*)((const char*)Bs + (wc + nn * 16 + l15) * 512 + bbase);
      acc0[nn] = __builtin_amdgcn_mfma_f32_16x16x32_bf16(af0, bf, acc0[nn], 0, 0, 0);
      acc1[nn] = __builtin_amdgcn_mfma_f32_16x16x32_bf16(af1, bf, acc1[nn], 0, 0, 0);
    }
  }
  // ---- epilogue: C/D layout col=lane&15, row=(lane>>4)*4+j ----
  int rb = rp * 128 + wr + slot * 4;
#pragma unroll
  for (int nn = 0; nn < 4; ++nn) {
    int gcol = cp * 128 + wc + nn * 16 + l15;
#pragma unroll
    for (int j = 0; j < 4; ++j) {
      size_t o0 = (size_t)(rb + j) * ldc + gcol;
      size_t o1 = (size_t)(rb + 16 + j) * ldc + gcol;
      if constexpr (__is_same(OutT, float)) {
        C[o0] = acc0[nn][j];
        C[o1] = acc1[nn][j];
      } else {
        C[o0] = __float2bfloat16(acc0[nn][j]);
        C[o1] = __float2bfloat16(acc1[nn][j]);
      }
    }
  }
}

// ---------------- masked cross-attention: one wave per cell, online softmax ---------------
__global__ __launch_bounds__(256) void attn_kernel(
    const float* __restrict__ lat,          // [1024][768]  q|k|v
    const __hip_bfloat16* __restrict__ kv,  // [m*n][512]   k|v
    const int* __restrict__ pts2,           // [MS][16]: w0=eff, w1..15 sorted pt indices
    __hip_bfloat16* __restrict__ attn_out, int n) {
  const float scale = 0.17677669529663687f;  // 1/sqrt(32)
  int wid = threadIdx.x >> 6;
  int lane = threadIdx.x & 63;
  int cellg = blockIdx.x * 4 + wid;
  int b = cellg >> 13;                 // S_=8192, cells per batch
  int c = cellg & (SP_ - 1);           // spatial index -> latent row
  int d0 = lane << 2;                  // 4 dims per lane

  const int* pp = pts2 + (size_t)cellg * P_;
  int4 h0 = *(const int4*)pp;          // eff, pt0, pt1, pt2 (broadcast load)
  int eff = h0.x;

  const float* latc = lat + c * 768 + d0;
  float4 q  = *(const float4*)latc;
  float4 kl = *(const float4*)(latc + 256);
  float4 vl = *(const float4*)(latc + 512);

  // grid-token logit -> init online-softmax state
  float part = q.x*kl.x + q.y*kl.y + q.z*kl.z + q.w*kl.w;
  part += __shfl_xor(part, 1);
  part += __shfl_xor(part, 2);
  part += __shfl_xor(part, 4);         // head-local (8 lanes = 32 dims)
  float mx = part * scale;
  float ssum = 1.f;
  float4 acc = vl;

  const unsigned short* kvp = (const unsigned short*)kv;
  size_t bbase = (size_t)b * n;

  int pt[4]; pt[0] = h0.y; pt[1] = h0.z; pt[2] = h0.w; pt[3] = 0;
  int done = 0, cap = 3;
  while (done < eff) {
    int np = eff - done; if (np > cap) np = cap;
    ushort4 kr[4], vr[4];
#pragma unroll
    for (int i = 0; i < 4; ++i) if (i < np) {
      size_t row = (bbase + (size_t)pt[i]) * 512;
      kr[i] = *(const ushort4*)(kvp + row + d0);
      vr[i] = *(const ushort4*)(kvp + row + 256 + d0);
    }
#pragma unroll
    for (int i = 0; i < 4; ++i) if (i < np) {
      float p = q.x*bf2f(kr[i].x) + q.y*bf2f(kr[i].y) + q.z*bf2f(kr[i].z) + q.w*bf2f(kr[i].w);
      p += __shfl_xor(p, 1);
      p += __shfl_xor(p, 2);
      p += __shfl_xor(p, 4);
      p *= scale;
      float m2 = fmaxf(mx, p);
      float corr = __expf(mx - m2);
      float e = __expf(p - m2);
      ssum = ssum * corr + e;
      acc.x = acc.x * corr + e * bf2f(vr[i].x);
      acc.y = acc.y * corr + e * bf2f(vr[i].y);
      acc.z = acc.z * corr + e * bf2f(vr[i].z);
      acc.w = acc.w * corr + e * bf2f(vr[i].w);
      mx = m2;
    }
    done += np;
    cap = 4;
    if (done < eff) {
      int4 h = *(const int4*)(pp + 1 + done);   // done in {3,7,11} -> aligned
      pt[0] = h.x; pt[1] = h.y; pt[2] = h.z; pt[3] = h.w;
    }
  }
  float inv = 1.f / ssum;
  ushort4 o;
  o.x = f2bf(acc.x * inv); o.y = f2bf(acc.y * inv);
  o.z = f2bf(acc.z * inv); o.w = f2bf(acc.w * inv);
  *(ushort4*)((unsigned short*)attn_out + (size_t)cellg * E_ + d0) = o;
}

// -------------------------------------------------------------------------------------------
extern "C" void kernel_launch(void* const* d_in, const int* in_sizes, int n_in,
                              void* d_out, int out_size, void* d_ws, size_t ws_size,
                              hipStream_t stream) {
  const float* x       = (const float*)d_in[0];
  const float* z       = (const float*)d_in[1];
  const float* tg      = (const float*)d_in[2];
  const float* latents = (const float*)d_in[3];
  const float* grid    = (const float*)d_in[4];
  const float* Wq      = (const float*)d_in[5];
  const float* Wk      = (const float*)d_in[6];
  const float* Wv      = (const float*)d_in[7];
  const float* Wo      = (const float*)d_in[8];

  int m = in_sizes[2] / T_;              // 4
  int n = in_sizes[1] / (m * E_);        // 16384
  int MS = m * S_;                       // 32768
  float* out = (float*)d_out;

  // ---- workspace carve (256B aligned) ----
  char* w = (char*)d_ws;
  auto alloc = [&](size_t bytes) { char* p = w; w += (bytes + 255) & ~(size_t)255; return p; };
  float* stats      = (float*)alloc((size_t)m * 8 * 4);
  int*   counts     = (int*)  alloc((size_t)MS * 4);
  int*   cell_raw   = (int*)  alloc((size_t)MS * P_ * 4);
  int*   pts2       = (int*)  alloc((size_t)MS * P_ * 4);
  unsigned short* wT = (unsigned short*)alloc((size_t)1024 * 256 * 2);
  float* lat        = (float*)alloc((size_t)SP_ * 768 * 4);
  __hip_bfloat16* kv       = (__hip_bfloat16*)alloc((size_t)m * n * 512 * 2);
  __hip_bfloat16* attn_out = (__hip_bfloat16*)alloc((size_t)MS * E_ * 2);

  hipMemsetAsync(counts, 0, (size_t)MS * 4, stream);
  stats_kernel<<<1, 64, 0, stream>>>(tg, grid, stats, m);

  int tot_xg = m * T_ * SP_;             // 32768 grid sites
  xgrid_kernel<<<(tot_xg + 255)/256, 256, 0, stream>>>(tg, grid, out, tot_xg);

  assign_kernel<<<(m*n + 255)/256, 256, 0, stream>>>(x, stats, counts, cell_raw, m, n);
  finalize_kernel<<<(MS + 255)/256, 256, 0, stream>>>(counts, cell_raw, pts2, MS);

  // weights: transpose + convert to bf16  [Wq|Wk|Wv|Wo]^T
  wtrans_kernel<<<64, 256, 0, stream>>>(Wq, Wk, Wv, Wo, wT);

  // latent projections fused: lat[1024,768] = latents @ [Wq|Wk|Wv]  (8 rp x 6 cp = 48 blocks)
  gemm_bpanel<float, float><<<48, 512, 0, stream>>>(latents, wT, lat, SP_, 768, 6);

  // point projections fused: kv[m*n,512] = z @ [Wk|Wv]  (512 rp x 4 cp = 2048 blocks)
  gemm_bpanel<float, __hip_bfloat16><<<2048, 512, 0, stream>>>(
      z, wT + (size_t)256*256, (__hip_bfloat16*)kv, m*n, 512, 4);

  // attention: one wave per cell
  attn_kernel<<<MS/4, 256, 0, stream>>>(lat, kv, pts2, attn_out, n);

  // output projection -> z_grid  (256 rp x 2 cp = 512 blocks)
  gemm_bpanel<__hip_bfloat16, float><<<512, 512, 0, stream>>>(
      attn_out, wT + (size_t)768*256, out + (size_t)tot_xg * 3, MS, 256, 2);
}